// Round 1
// 3855.668 us; speedup vs baseline: 1.5254x; 1.5254x over previous
//
#include <hip/hip_runtime.h>
#include <math.h>

#define kB 2
#define kH 256
#define kW 256
#define kHW 65536
#define kHp 258            // padded rows: 1-px zero halo top/bottom
#define kWp 258            // padded cols: 1-px zero halo left/right
#define kNSPIX 256
#define kC 20
#define kNITER 10

typedef unsigned int uint;
typedef unsigned short ushort;

using f32x4  = __attribute__((ext_vector_type(4))) float;
using bf16x8 = __attribute__((ext_vector_type(8))) __bf16;

__device__ __forceinline__ ushort f2bf(float f) {
    uint u = __float_as_uint(f);
    u = (u + 0x7FFFu + ((u >> 16) & 1u)) >> 16;
    return (ushort)u;
}
__device__ __forceinline__ float bf2f(uint h) {
    return __uint_as_float(h << 16);
}

// async global->LDS, 16B per lane; LDS dest must be wave-uniform base + lane*16
__device__ __forceinline__ void gld16(const void* g, void* l) {
    __builtin_amdgcn_global_load_lds(
        (const __attribute__((address_space(1))) unsigned int*)g,
        (__attribute__((address_space(3))) unsigned int*)l, 16, 0, 0);
}

// ---------------------------------------------------------------------------
// feats fp32 NCHW -> bf16 NHWC (ci contiguous), zero-padded to Cin_pad,
// written into the PADDED (kHp x kWp) pixel grid (interior only).
// grid: (Cin_pad/32, HW/64, B)
// ---------------------------------------------------------------------------
__global__ __launch_bounds__(256) void xtrans(
    const float* __restrict__ src, ushort* __restrict__ dst,
    int Cin_real, int Cin_pad)
{
    __shared__ float s[64][33];
    const int ci0 = blockIdx.x * 32;
    const int p0  = blockIdx.y * 64;
    const int b   = blockIdx.z;
    const int tid = threadIdx.x;
    for (int e = tid; e < 2048; e += 256) {
        int ci = e >> 6, px = e & 63;
        int cig = ci0 + ci;
        float v = 0.f;
        if (cig < Cin_real) v = src[((long)b * Cin_real + cig) * kHW + p0 + px];
        s[px][ci] = v;
    }
    __syncthreads();
    const int px = tid >> 2, g = tid & 3;
    uint4 o;
    o.x = (uint)f2bf(s[px][g*8+0]) | ((uint)f2bf(s[px][g*8+1]) << 16);
    o.y = (uint)f2bf(s[px][g*8+2]) | ((uint)f2bf(s[px][g*8+3]) << 16);
    o.z = (uint)f2bf(s[px][g*8+4]) | ((uint)f2bf(s[px][g*8+5]) << 16);
    o.w = (uint)f2bf(s[px][g*8+6]) | ((uint)f2bf(s[px][g*8+7]) << 16);
    const int y = p0 >> 8;
    const int x = (p0 & 255) + px;
    *(uint4*)(dst + ((long)(b * kHp + y + 1) * kWp + x + 1) * Cin_pad + ci0 + g * 8) = o;
}

// ---------------------------------------------------------------------------
// W fp32 [co][ci][tap] -> bf16 Wt[tap][co_pad][ci_pad], zero-padded.
// ---------------------------------------------------------------------------
__global__ __launch_bounds__(256) void wtrans(
    const float* __restrict__ W, ushort* __restrict__ Wt,
    int Cout_real, int Cin_real, int Cout_pad, int Cin_pad)
{
    long idx = (long)blockIdx.x * 256 + threadIdx.x;
    long total = (long)9 * Cout_pad * Cin_pad;
    if (idx >= total) return;
    int t   = (int)(idx / ((long)Cout_pad * Cin_pad));
    long r  = idx - (long)t * Cout_pad * Cin_pad;
    int co  = (int)(r / Cin_pad);
    int ci  = (int)(r - (long)co * Cin_pad);
    float v = 0.f;
    if (co < Cout_real && ci < Cin_real) v = W[((long)co * Cin_real + ci) * 9 + t];
    Wt[idx] = f2bf(v);
}

// ---------------------------------------------------------------------------
// Zero the 1-px halo border of a padded NHWC buffer.
// border pixels per image: 2*258 (top/bottom) + 2*256 (left/right) = 1028
// grid: (5, Cpad/8, B)
// ---------------------------------------------------------------------------
__global__ __launch_bounds__(256) void zero_border(ushort* __restrict__ buf, int Cpad)
{
    int e = blockIdx.x * 256 + threadIdx.x;
    if (e >= 1028) return;
    int gq = blockIdx.y;
    int b  = blockIdx.z;
    int y, x;
    if (e < 516) { y = (e < 258) ? 0 : 257; x = (e < 258) ? e : e - 258; }
    else         { int f = e - 516; y = 1 + (f >> 1); x = (f & 1) ? 257 : 0; }
    uint4 z = {0u, 0u, 0u, 0u};
    *(uint4*)(buf + ((long)(b * kHp + y) * kWp + x) * Cpad + (long)gq * 8) = z;
}

// ---------------------------------------------------------------------------
// Implicit-GEMM conv3x3 SAME, bf16 MFMA 16x16x32, padded NHWC.
// Block: 64 cout x 128 px. 4 waves, wave = 32co x 64px.
// K-loop restructured ky-major: chunk = (ky, 32ci); per chunk stage
//   B: 1 input row, 130 px  (halo via padded layout, no bounds checks)
//   A: 3 taps (ky*3+kx) x 64co x 32ci
// Staging via async global_load_lds (width 16), double-buffered, raw
// s_barrier + counted vmcnt (T3/T4 2-phase): loads for chunk q+1 stay in
// flight while chunk q computes. LDS 43KB -> 3 blocks/CU.
// Swizzle: chunk = quad ^ ((idx>>1)&3) applied on the GLOBAL source (LDS dest
// must stay linear for global_load_lds) -> 2-way (free) bank aliasing.
// grid: (Cout_pad/64, 512, B)
// ---------------------------------------------------------------------------
__global__ __launch_bounds__(256, 3) void conv_mfma(
    const ushort* __restrict__ Xt, const ushort* __restrict__ Wt,
    ushort* __restrict__ Yt, float* __restrict__ stats,
    int Cin_pad, int Cout_pad, int nkc)
{
    __shared__ __align__(16) ushort As[2][6144];  // [buf][tap3][co64][ci32 swz]
    __shared__ __align__(16) ushort Bs[2][4608];  // [buf][px144][ci32 swz]

    const int tid  = threadIdx.x;
    const int lane = tid & 63;
    const int wave = tid >> 6;
    const int l15  = lane & 15;
    const int quad = lane >> 4;
    const int co_w = (wave >> 1) * 32;
    const int px_w = (wave & 1) * 64;
    const int co0  = blockIdx.x * 64;
    const int py   = blockIdx.y >> 1;
    const int x0   = (blockIdx.y & 1) * 128;
    const int b    = blockIdx.z;
    const int ca8  = (quad ^ ((l15 >> 1) & 3)) * 8;   // A-read chunk offset

    f32x4 acc[2][4];
    #pragma unroll
    for (int i = 0; i < 2; ++i)
        #pragma unroll
        for (int j = 0; j < 4; ++j) acc[i][j] = (f32x4)0.0f;

    // stage chunk (kyv, ci0) into buffer s.
    // per-wave global_load_lds count: wave0 = 6, waves1-3 = 5.
    auto stage = [&](int s, int kyv, int ci0) {
        // B: input row global y = py+kyv-1 -> padded row py+kyv; 130 px from x0-1.
        const ushort* xrow = Xt + ((long)(b * kHp + py + kyv) * kWp + x0) * Cin_pad + ci0;
        ushort* bd = &Bs[s][0];
        {
            int u = tid;        int px = u >> 2, gs = u & 3;
            gld16(xrow + (long)px * Cin_pad + ((gs ^ ((px >> 1) & 3)) * 8), bd + u * 8);
        }
        {
            int u = tid + 256;  int px = u >> 2, gs = u & 3;
            gld16(xrow + (long)px * Cin_pad + ((gs ^ ((px >> 1) & 3)) * 8), bd + u * 8);
        }
        if (tid < 64) {         // wave-uniform (wave 0 only)
            int u = tid + 512;  int px = u >> 2; px = px > 129 ? 129 : px;  // slots >129 unused
            int gs = u & 3;
            gld16(xrow + (long)px * Cin_pad + ((gs ^ ((px >> 1) & 3)) * 8), bd + u * 8);
        }
        // A: taps kyv*3 + {0,1,2}
        const ushort* wb = Wt + ((long)(kyv * 3) * Cout_pad + co0) * Cin_pad + ci0;
        ushort* ad = &As[s][0];
        #pragma unroll
        for (int r = 0; r < 3; ++r) {
            int u = tid + r * 256;
            int tl = u >> 8, co = (u >> 2) & 63, gs = u & 3;
            gld16(wb + ((long)tl * Cout_pad + co) * Cin_pad + ((gs ^ ((co >> 1) & 3)) * 8), ad + u * 8);
        }
    };

    int ky = 0, cc = 0;
    stage(0, 0, 0);
    const int NCH = 3 * nkc;
    for (int q = 0; q < NCH; ++q) {
        const int s = q & 1;
        int ky_n = ky, cc_n = cc + 1;
        if (cc_n == nkc) { cc_n = 0; ++ky_n; }
        if (q + 1 < NCH) {
            stage(s ^ 1, ky_n, cc_n * 32);
            // current buffer's loads (issued last iter) are the oldest; keep
            // the new chunk's loads in flight across the barrier.
            asm volatile("s_waitcnt vmcnt(5)" ::: "memory");
        } else {
            asm volatile("s_waitcnt vmcnt(0)" ::: "memory");
        }
        __builtin_amdgcn_s_barrier();
        asm volatile("" ::: "memory");

        const ushort* Ab = &As[s][0];
        const ushort* Bb = &Bs[s][0];
        #pragma unroll
        for (int kx = 0; kx < 3; ++kx) {
            bf16x8 a0 = *(const bf16x8*)(Ab + (kx * 64 + co_w + l15) * 32 + ca8);
            bf16x8 a1 = *(const bf16x8*)(Ab + (kx * 64 + co_w + 16 + l15) * 32 + ca8);
            #pragma unroll
            for (int j = 0; j < 4; ++j) {
                int px = px_w + j * 16 + l15 + kx;     // local = global - (x0-1)
                bf16x8 bb = *(const bf16x8*)(Bb + px * 32 + ((quad ^ ((px >> 1) & 3)) * 8));
                acc[0][j] = __builtin_amdgcn_mfma_f32_16x16x32_bf16(a0, bb, acc[0][j], 0, 0, 0);
                acc[1][j] = __builtin_amdgcn_mfma_f32_16x16x32_bf16(a1, bb, acc[1][j], 0, 0, 0);
            }
        }
        asm volatile("s_waitcnt lgkmcnt(0)" ::: "memory");  // my ds_reads landed
        __builtin_amdgcn_s_barrier();                       // buffer safe to overwrite
        asm volatile("" ::: "memory");
        ky = ky_n; cc = cc_n;
    }

    // ---- epilogue: padded NHWC bf16 store + per-channel (sum,sumsq) atomics ----
    const long rowbase = (long)(b * kHp + py + 1) * kWp + x0 + 1 + px_w;
    #pragma unroll
    for (int i = 0; i < 2; ++i) {
        #pragma unroll
        for (int reg = 0; reg < 4; ++reg) {
            int co_r = co0 + co_w + i * 16 + quad * 4 + reg;
            float s = 0.f, s2 = 0.f;
            #pragma unroll
            for (int j = 0; j < 4; ++j) {
                float v = acc[i][j][reg];
                s += v;
                s2 = fmaf(v, v, s2);
                Yt[(rowbase + j * 16 + l15) * Cout_pad + co_r] = f2bf(v);
            }
            #pragma unroll
            for (int off = 1; off <= 8; off <<= 1) {
                s  += __shfl_xor(s, off);
                s2 += __shfl_xor(s2, off);
            }
            if (l15 == 0) {
                atomicAdd(&stats[co_r], s);
                atomicAdd(&stats[Cout_pad + co_r], s2);
            }
        }
    }
}

// ---------------------------------------------------------------------------
__global__ void finalize_stats(const float* __restrict__ stats,
                               float* __restrict__ murs, int Cout_pad)
{
    int c = blockIdx.x * 256 + threadIdx.x;
    if (c >= Cout_pad) return;
    const float invN = 1.0f / (float)(kB * kHW);
    float mu  = stats[c] * invN;
    float var = stats[Cout_pad + c] * invN - mu * mu;
    murs[c] = mu;
    murs[Cout_pad + c] = rsqrtf(var + 1e-5f);
}

// ---------------------------------------------------------------------------
// BN + ReLU in place on padded NHWC bf16 (interior pixels only; the halo
// border must stay exactly zero for the next conv's SAME padding).
// ---------------------------------------------------------------------------
__global__ __launch_bounds__(256) void bn_relu_nhwc(
    ushort* __restrict__ Y, const float* __restrict__ murs,
    const float* __restrict__ g, const float* __restrict__ bia,
    int C_real, int C_pad)
{
    long idx = (long)blockIdx.x * 256 + threadIdx.x;
    const int ngc = C_pad >> 3;
    long total = (long)kB * kHW * ngc;
    if (idx >= total) return;
    int cg = (int)(idx % ngc);
    long p  = idx / ngc;
    int b  = (int)(p >> 16);
    int pp = (int)(p & 65535);
    int y = pp >> 8, x = pp & 255;
    ushort* ptr = Y + ((long)(b * kHp + y + 1) * kWp + x + 1) * C_pad + (long)cg * 8;
    uint4 v = *(uint4*)ptr;
    uint w[4] = {v.x, v.y, v.z, v.w};
    uint o[4];
    #pragma unroll
    for (int q = 0; q < 4; ++q) {
        int c0 = cg * 8 + q * 2;
        int c1 = c0 + 1;
        float f0 = 0.f, f1 = 0.f;
        if (c0 < C_real)
            f0 = fmaxf((bf2f(w[q] & 0xFFFFu) - murs[c0]) * murs[C_pad + c0] * g[c0] + bia[c0], 0.f);
        if (c1 < C_real)
            f1 = fmaxf((bf2f(w[q] >> 16) - murs[c1]) * murs[C_pad + c1] * g[c1] + bia[c1], 0.f);
        o[q] = (uint)f2bf(f0) | ((uint)f2bf(f1) << 16);
    }
    uint4 ov = {o[0], o[1], o[2], o[3]};
    *(uint4*)ptr = ov;
}

// ---------------------------------------------------------------------------
// conv3 output (padded NHWC bf16, C_pad=64) -> BN+ReLU -> pf planar fp32 ch 0..14
// ---------------------------------------------------------------------------
__global__ __launch_bounds__(256) void bn_to_pf(
    const ushort* __restrict__ y3, const float* __restrict__ murs,
    const float* __restrict__ g, const float* __restrict__ bia,
    float* __restrict__ pf)
{
    long idx = (long)blockIdx.x * 256 + threadIdx.x;
    if (idx >= (long)kB * 15 * kHW) return;
    int b  = (int)(idx / (15 * kHW));
    long r = idx - (long)b * 15 * kHW;
    int ch = (int)(r / kHW);
    long p = r - (long)ch * kHW;
    int y = (int)(p >> 8), x = (int)(p & 255);
    float v = bf2f((uint)y3[((long)(b * kHp + y + 1) * kWp + x + 1) * 64 + ch]);
    v = fmaxf((v - murs[ch]) * murs[64 + ch] * g[ch] + bia[ch], 0.f);
    pf[((long)b * kC + ch) * kHW + p] = v;
}

// ---------------------------------------------------------------------------
__global__ __launch_bounds__(256) void fill_extra(
    const float* __restrict__ x, const float* __restrict__ coords, float* __restrict__ pf)
{
    long idx = (long)blockIdx.x * 256 + threadIdx.x;
    if (idx >= (long)kB * 5 * kHW) return;
    int b   = (int)(idx / (5 * kHW));
    long rem = idx - (long)b * 5 * kHW;
    int c   = (int)(rem / kHW);
    long p  = rem - (long)c * kHW;
    float v = (c < 3) ? x[((long)b * 3 + c) * kHW + p]
                      : coords[((long)b * 2 + (c - 3)) * kHW + p];
    pf[((long)b * kC + 15 + c) * kHW + p] = v;
}

// ---------------------------------------------------------------------------
__global__ __launch_bounds__(256) void cid_kernel(float* __restrict__ out_cid)
{
    int idx = blockIdx.x * 256 + threadIdx.x;
    if (idx >= 9 * kHW) return;
    int k = idx / kHW, p = idx - k * kHW;
    int r = p >> 8, c = p & 255;
    int rr = (r >> 4) + k / 3 - 1;
    int cc = (c >> 4) + k % 3 - 1;
    rr = rr < 0 ? 0 : (rr > 15 ? 15 : rr);
    cc = cc < 0 ? 0 : (cc > 15 ? 15 : cc);
    out_cid[idx] = (float)(rr * 16 + cc);
}

// ---------------------------------------------------------------------------
__global__ __launch_bounds__(256) void cent_init(
    const float* __restrict__ pf, float* __restrict__ cent)
{
    int idx = blockIdx.x * 256 + threadIdx.x;
    if (idx >= kB * kC * kNSPIX) return;
    int b   = idx / (kC * kNSPIX);
    int rem = idx - b * (kC * kNSPIX);
    int c   = rem / kNSPIX;
    int s   = rem - c * kNSPIX;
    int sr = s >> 4, sc = s & 15;
    const float* base = pf + ((long)b * kC + c) * kHW;
    float sum = 0.f;
    for (int ry = 0; ry < 16; ++ry)
        for (int rx = 0; rx < 16; ++rx)
            sum += base[(sr * 16 + ry) * kW + sc * 16 + rx];
    cent[idx] = sum * (1.0f / 256.0f);
}

// ---------------------------------------------------------------------------
__global__ __launch_bounds__(256) void ssn_softmax(
    const float* __restrict__ pf, const float* __restrict__ cent, float* __restrict__ aff)
{
    __shared__ float s_cent[kC][kNSPIX];
    const int b   = blockIdx.y;
    const int tid = threadIdx.x;
    const float* cb = cent + (long)b * kC * kNSPIX;
    for (int i = tid; i < kC * kNSPIX; i += 256)
        s_cent[i >> 8][i & 255] = cb[i];
    __syncthreads();

    const int p  = blockIdx.x * 256 + tid;
    const int r  = p >> 8, c = p & 255;
    const int r0 = r >> 4, c0 = c >> 4;

    float f[kC];
    const float* pb = pf + (long)b * kC * kHW + p;
    #pragma unroll
    for (int ch = 0; ch < kC; ++ch) f[ch] = pb[(long)ch * kHW];

    float dist[9];
    bool  val[9];
    float mx = -1e30f;
    #pragma unroll
    for (int k = 0; k < 9; ++k) {
        int rr = r0 + k / 3 - 1;
        int cc = c0 + k % 3 - 1;
        bool v = (rr >= 0 && rr < 16 && cc >= 0 && cc < 16);
        val[k] = v;
        int sid = v ? rr * 16 + cc : 0;
        float d = 0.f;
        #pragma unroll
        for (int ch = 0; ch < kC; ++ch) {
            float t = f[ch] - s_cent[ch][sid];
            d = fmaf(t, t, d);
        }
        dist[k] = d;
        if (v) mx = fmaxf(mx, -d);
    }
    float e[9], sum = 0.f;
    #pragma unroll
    for (int k = 0; k < 9; ++k) {
        e[k] = val[k] ? expf(-dist[k] - mx) : 0.f;
        sum += e[k];
    }
    float inv = 1.0f / sum;
    float* ab = aff + (long)b * 9 * kHW + p;
    #pragma unroll
    for (int k = 0; k < 9; ++k) ab[(long)k * kHW] = e[k] * inv;
}

// ---------------------------------------------------------------------------
__global__ __launch_bounds__(256) void ssn_update(
    const float* __restrict__ pf, const float* __restrict__ aff, float* __restrict__ cent)
{
    const int b  = blockIdx.y;
    const int s  = blockIdx.x;
    const int sr = s >> 4, sc = s & 15;
    const int tid = threadIdx.x;
    const int ty = tid >> 4, tx = tid & 15;

    float acc[kC + 1];
    #pragma unroll
    for (int i = 0; i <= kC; ++i) acc[i] = 0.f;

    #pragma unroll
    for (int k = 0; k < 9; ++k) {
        int dr = k / 3 - 1, dc = k % 3 - 1;
        int br = sr - dr, bc = sc - dc;
        if (br < 0 || br > 15 || bc < 0 || bc > 15) continue;
        int p = (br * 16 + ty) * kW + bc * 16 + tx;
        float w = aff[((long)b * 9 + k) * kHW + p];
        const float* pb = pf + (long)b * kC * kHW + p;
        acc[kC] += w;
        #pragma unroll
        for (int ch = 0; ch < kC; ++ch)
            acc[ch] = fmaf(w, pb[(long)ch * kHW], acc[ch]);
    }

    #pragma unroll
    for (int off = 32; off >= 1; off >>= 1)
        #pragma unroll
        for (int ch = 0; ch <= kC; ++ch)
            acc[ch] += __shfl_down(acc[ch], off);

    __shared__ float part[4][kC + 1];
    int wid = tid >> 6;
    if ((tid & 63) == 0)
        #pragma unroll
        for (int ch = 0; ch <= kC; ++ch) part[wid][ch] = acc[ch];
    __syncthreads();
    if (tid < kC) {
        float num = part[0][tid] + part[1][tid] + part[2][tid] + part[3][tid];
        float den = part[0][kC] + part[1][kC] + part[2][kC] + part[3][kC];
        cent[((long)b * kC + tid) * kNSPIX + s] = num / (den + 1e-16f);
    }
}

// ---------------------------------------------------------------------------
extern "C" void kernel_launch(void* const* d_in, const int* in_sizes, int n_in,
                              void* d_out, int out_size, void* d_ws, size_t ws_size,
                              hipStream_t stream)
{
    const float* x      = (const float*)d_in[0];
    const float* coords = (const float*)d_in[1];
    const float* feats  = (const float*)d_in[2];
    const float* W1 = (const float*)d_in[3];
    const float* g1 = (const float*)d_in[4];
    const float* b1 = (const float*)d_in[5];
    const float* W2 = (const float*)d_in[6];
    const float* g2 = (const float*)d_in[7];
    const float* b2 = (const float*)d_in[8];
    const float* W3 = (const float*)d_in[9];
    const float* g3 = (const float*)d_in[10];
    const float* b3 = (const float*)d_in[11];

    // ---- workspace layout (bytes); padded pixel grid = kHp*kWp ----
    const long HPWP = (long)kHp * kWp;   // 66564
    char* ws = (char*)d_ws;
    ushort* Xt1 = (ushort*)ws;  ws += (long)kB * HPWP * 1056 * 2;
    ushort* Wt1 = (ushort*)ws;  ws += (long)9 * 512 * 1056 * 2;
    ushort* y1t = (ushort*)ws;  ws += (long)kB * HPWP * 512 * 2;
    ushort* Wt2 = (ushort*)ws;  ws += (long)9 * 128 * 512 * 2;
    ushort* y2t = (ushort*)ws;  ws += (long)kB * HPWP * 128 * 2;
    ushort* Wt3 = (ushort*)ws;  ws += (long)9 * 64 * 128 * 2;
    ushort* y3t = (ushort*)ws;  ws += (long)kB * HPWP * 64 * 2;
    float*  pf  = (float*)ws;   ws += (long)2 * kC * kHW * 4;
    float* stats1 = (float*)ws; ws += 1024 * 4;
    float* stats2 = (float*)ws; ws += 256 * 4;
    float* stats3 = (float*)ws; ws += 128 * 4;
    float* murs1  = (float*)ws; ws += 1024 * 4;
    float* murs2  = (float*)ws; ws += 256 * 4;
    float* murs3  = (float*)ws; ws += 128 * 4;

    hipMemsetAsync(stats1, 0, (1024 + 256 + 128 + 1024 + 256 + 128) * 4, stream);

    // ---- output layout ----
    float* aff_out  = (float*)d_out;
    float* cid_out  = aff_out + (long)kB * 9 * kHW;
    float* cent_out = cid_out + (long)9 * kHW;

    // ---- zero halo borders of conv inputs ----
    zero_border<<<dim3(5, 132, kB), 256, 0, stream>>>(Xt1, 1056);
    zero_border<<<dim3(5,  64, kB), 256, 0, stream>>>(y1t, 512);
    zero_border<<<dim3(5,  16, kB), 256, 0, stream>>>(y2t, 128);

    // ---- pre-passes ----
    xtrans<<<dim3(33, 1024, kB), 256, 0, stream>>>(feats, Xt1, 1029, 1056);
    wtrans<<<(int)(((long)9 * 512 * 1056 + 255) / 256), 256, 0, stream>>>(W1, Wt1, 500, 1029, 512, 1056);
    wtrans<<<(int)(((long)9 * 128 * 512 + 255) / 256), 256, 0, stream>>>(W2, Wt2, 100, 500, 128, 512);
    wtrans<<<(int)(((long)9 * 64 * 128 + 255) / 256), 256, 0, stream>>>(W3, Wt3, 15, 100, 64, 128);

    // ---- conv1: 1029 -> 500 ----
    conv_mfma<<<dim3(8, 512, kB), 256, 0, stream>>>(Xt1, Wt1, y1t, stats1, 1056, 512, 33);
    finalize_stats<<<2, 256, 0, stream>>>(stats1, murs1, 512);
    bn_relu_nhwc<<<(int)(((long)kB * kHW * 64 + 255) / 256), 256, 0, stream>>>(y1t, murs1, g1, b1, 500, 512);

    // ---- conv2: 500 -> 100 ----
    conv_mfma<<<dim3(2, 512, kB), 256, 0, stream>>>(y1t, Wt2, y2t, stats2, 512, 128, 16);
    finalize_stats<<<1, 256, 0, stream>>>(stats2, murs2, 128);
    bn_relu_nhwc<<<(int)(((long)kB * kHW * 16 + 255) / 256), 256, 0, stream>>>(y2t, murs2, g2, b2, 100, 128);

    // ---- conv3: 100 -> 15 ----
    conv_mfma<<<dim3(1, 512, kB), 256, 0, stream>>>(y2t, Wt3, y3t, stats3, 128, 64, 4);
    finalize_stats<<<1, 256, 0, stream>>>(stats3, murs3, 64);
    bn_to_pf<<<(int)(((long)kB * 15 * kHW + 255) / 256), 256, 0, stream>>>(y3t, murs3, g3, b3, pf);

    // ---- pf extra channels, cid, centroids ----
    fill_extra<<<(int)(((long)kB * 5 * kHW + 255) / 256), 256, 0, stream>>>(x, coords, pf);
    cid_kernel<<<(9 * kHW + 255) / 256, 256, 0, stream>>>(cid_out);
    cent_init<<<(kB * kC * kNSPIX + 255) / 256, 256, 0, stream>>>(pf, cent_out);

    // ---- SSN iterations ----
    for (int it = 0; it < kNITER; ++it) {
        ssn_softmax<<<dim3(kHW / 256, kB), 256, 0, stream>>>(pf, cent_out, aff_out);
        ssn_update<<<dim3(kNSPIX, kB), 256, 0, stream>>>(pf, aff_out, cent_out);
    }
}